// Round 3
// baseline (978.020 us; speedup 1.0000x reference)
//
#include <hip/hip_runtime.h>

// HeteroGraphSAGE on MI355X — fp32 I/O, bf16 MFMA internals.
//
// Stages:
//   1. pack_all: fp32 weights -> bf16 MFMA B-fragment order (10 slots, 320 KB)
//   2. build_buckets: per-destination neighbor lists, CAP=64
//   3. sage_fused x4: per-wave gather-mean into bf16 LDS tile -> MFMA K-loop
//      out = relu(mean @ Wl + x_dst @ Wr + bl), N=128
//   4. head_fused x2: hidden = relu(X @ [cW1|rW1] + [cb1|rb1]) tile in LDS,
//      then per-row second-layer dots + sigmoid
//
// ws layout (bytes), total ~40.4 MiB:
//   cnt_m    @ 0        (50000*4)
//   cnt_c    @ 256K     (100000*4)
//   bucket_m @ 1  MiB   (50000*64*4  = 12.8 MB, u32 card ids)
//   bucket_c @ 14 MiB   (100000*64*2 = 12.8 MB, u16 merchant ids)
//   h_m      @ 27 MiB   (50000*128*2 = 12.8 MB, bf16)
//   packed   @ 40 MiB   (10 * 32 KiB bf16)
// h_c (layer-0 card hidden) lives as fp32 in d_out's h_c2 slot; layer-1
// merchant gathers it, then layer-1 card updates it in place (row-disjoint).

typedef unsigned short u16;
typedef unsigned int u32;
typedef short bf16x8 __attribute__((ext_vector_type(8)));
typedef float f32x4 __attribute__((ext_vector_type(4)));

#define CAP 64
#define LDS_PAD 8

__device__ __forceinline__ float bf2f(u16 u) {
    union { u32 i; float f; } v; v.i = ((u32)u) << 16; return v.f;
}
__device__ __forceinline__ u16 f2bf(float f) {
    union { float f; u32 i; } v; v.f = f;
    u32 i = v.i;
    return (u16)((i + 0x7FFFu + ((i >> 16) & 1u)) >> 16);   // RNE
}
__device__ __forceinline__ bf16x8 cvt8(const float* p) {
    bf16x8 r;
#pragma unroll
    for (int i = 0; i < 8; ++i) r[i] = (short)f2bf(p[i]);
    return r;
}

// ---------------- weight packing: fp32 W[K,Nsrc] -> bf16 MFMA B fragments ----------------
// packed[((kt*8 + ntOff+ntl)*64 + lane)*8 + j] = bf16(W[(kt*32 + (lane>>4)*8 + j)*Nsrc + ntl*16 + (lane&15)])
struct PackDesc { const float* src; u16* dst; int K; int Nsrc; int ntOff; };
struct PackArgs { PackDesc d[12]; };

__global__ void __launch_bounds__(256) pack_all(PackArgs pa) {
    PackDesc pd = pa.d[blockIdx.y];
    int idx = blockIdx.x * 256 + threadIdx.x;          // < 16384
    int j = idx & 7;
    int lane = (idx >> 3) & 63;
    int t = idx >> 9;
    int nLocal = pd.Nsrc >> 4;
    int ntl = t % nLocal;
    int kt = t / nLocal;
    if (kt >= (pd.K >> 5)) return;
    int k = kt * 32 + ((lane >> 4) << 3) + j;
    int n = ntl * 16 + (lane & 15);
    pd.dst[(((kt * 8 + pd.ntOff + ntl) * 64) + lane) * 8 + j] = f2bf(pd.src[k * pd.Nsrc + n]);
}

// ---------------- bucket build ----------------
__global__ void __launch_bounds__(256) build_buckets(
    const int* __restrict__ src_cm, const int* __restrict__ dst_cm,
    const int* __restrict__ src_mc, const int* __restrict__ dst_mc,
    int* __restrict__ cnt_m, u32* __restrict__ bucket_m,
    int* __restrict__ cnt_c, u16* __restrict__ bucket_c, int E)
{
    int i = blockIdx.x * 256 + threadIdx.x;
    if (i < E) {
        int d = dst_cm[i];
        int slot = atomicAdd(&cnt_m[d], 1);
        if (slot < CAP) bucket_m[(size_t)d * CAP + slot] = (u32)src_cm[i];
    } else if (i < 2 * E) {
        int j = i - E;
        int d = dst_mc[j];
        int slot = atomicAdd(&cnt_c[d], 1);
        if (slot < CAP) bucket_c[(size_t)d * CAP + slot] = (u16)src_mc[j];
    }
}

// ---------------- fused SAGE layer ----------------
// out[M,128] = relu(mean_nbr(Xsrc) @ Wl + Xdst @ Wr + bias)
// SRCF/DSTF/OUTF: fp32 (true) or bf16 (false) for gather-source / lin_r-source / output.
template<typename IdxT, bool SRCF, bool DSTF, bool OUTF>
__global__ void __launch_bounds__(256) sage_fused(
    const void* __restrict__ Xsrc_, const IdxT* __restrict__ adj,
    const int* __restrict__ cnt,
    const u16* __restrict__ Wlp, const void* __restrict__ Xdst_,
    const u16* __restrict__ Wrp, const float* __restrict__ bias,
    void* __restrict__ out_, int M, int K)
{
    __shared__ u16 lds[4][16][128 + LDS_PAD];
    const int lane = threadIdx.x & 63;
    const int wv = threadIdx.x >> 6;
    const int m0 = (blockIdx.x * 4 + wv) * 16;
    const bool active = (m0 < M);
    const int quad = lane >> 4;
    const int l15 = lane & 15;

    if (active) {
        for (int r = 0; r < 16; ++r) {
            int node = m0 + r;
            int c = cnt[node];
            int cc = min(c, CAP);
            int sidx = (lane < cc) ? (int)adj[(size_t)node * CAP + lane] : 0;
            float inv = 1.f / (float)max(c, 1);
            if (K == 128) {
                float a0 = 0.f, a1 = 0.f;
                for (int k = 0; k < cc; ++k) {
                    int s = __shfl(sidx, k);
                    if (SRCF) {
                        float2 v = *reinterpret_cast<const float2*>((const float*)Xsrc_ + (size_t)s * 128 + 2 * lane);
                        a0 += v.x; a1 += v.y;
                    } else {
                        u32 v = *reinterpret_cast<const u32*>((const u16*)Xsrc_ + (size_t)s * 128 + 2 * lane);
                        a0 += bf2f((u16)(v & 0xffffu));
                        a1 += bf2f((u16)(v >> 16));
                    }
                }
                u32 o = (u32)f2bf(a0 * inv) | ((u32)f2bf(a1 * inv) << 16);
                *reinterpret_cast<u32*>(&lds[wv][r][2 * lane]) = o;
            } else {  // K == 64
                float a = 0.f;
                for (int k = 0; k < cc; ++k) {
                    int s = __shfl(sidx, k);
                    if (SRCF) a += ((const float*)Xsrc_)[(size_t)s * 64 + lane];
                    else      a += bf2f(((const u16*)Xsrc_)[(size_t)s * 64 + lane]);
                }
                lds[wv][r][lane] = f2bf(a * inv);
            }
        }
    }
    __syncthreads();
    if (!active) return;

    const int KT = K >> 5;
    f32x4 acc[8];
#pragma unroll
    for (int i = 0; i < 8; ++i) acc[i] = (f32x4){0.f, 0.f, 0.f, 0.f};

    for (int kt = 0; kt < KT; ++kt) {
        bf16x8 a = *reinterpret_cast<const bf16x8*>(&lds[wv][l15][kt * 32 + quad * 8]);
#pragma unroll
        for (int nt = 0; nt < 8; ++nt) {
            bf16x8 b = *reinterpret_cast<const bf16x8*>(Wlp + (size_t)(((kt * 8 + nt) * 64 + lane) * 8));
            acc[nt] = __builtin_amdgcn_mfma_f32_16x16x32_bf16(a, b, acc[nt], 0, 0, 0);
        }
    }
    for (int kt = 0; kt < KT; ++kt) {
        bf16x8 a;
        if (DSTF) a = cvt8((const float*)Xdst_ + (size_t)(m0 + l15) * K + kt * 32 + quad * 8);
        else      a = *reinterpret_cast<const bf16x8*>((const u16*)Xdst_ + (size_t)(m0 + l15) * K + kt * 32 + quad * 8);
#pragma unroll
        for (int nt = 0; nt < 8; ++nt) {
            bf16x8 b = *reinterpret_cast<const bf16x8*>(Wrp + (size_t)(((kt * 8 + nt) * 64 + lane) * 8));
            acc[nt] = __builtin_amdgcn_mfma_f32_16x16x32_bf16(a, b, acc[nt], 0, 0, 0);
        }
    }
    // epilogue: C/D layout col = lane&15 (within 16-col tile), row = quad*4 + r
#pragma unroll
    for (int nt = 0; nt < 8; ++nt) {
        int col = nt * 16 + l15;
        float bv = bias[col];
#pragma unroll
        for (int r = 0; r < 4; ++r) {
            int row = m0 + quad * 4 + r;
            float v = fmaxf(acc[nt][r] + bv, 0.f);
            if (OUTF) ((float*)out_)[(size_t)row * 128 + col] = v;
            else      ((u16*)out_)[(size_t)row * 128 + col] = f2bf(v);
        }
    }
}

// ---------------- fused classifier + risk heads (X fp32) ----------------
// hidden = relu(X @ [cW1|rW1] + [cb1|rb1])  (16x128 tile per wave, into LDS),
// then per row: pred = hidden[0:64] @ cW2 + cb2 ; risk = sigmoid(hidden[64:128] @ rW2 + rb2)
__global__ void __launch_bounds__(256) head_fused(
    const float* __restrict__ X, const u16* __restrict__ W1p,
    const float* __restrict__ b1a, const float* __restrict__ b1b,
    const float* __restrict__ cW2, const float* __restrict__ cb2,
    const float* __restrict__ rW2, const float* __restrict__ rb2,
    float* __restrict__ pred, float* __restrict__ risk, int M)
{
    __shared__ u16 lds[4][16][128 + LDS_PAD];
    const int lane = threadIdx.x & 63;
    const int wv = threadIdx.x >> 6;
    const int m0 = (blockIdx.x * 4 + wv) * 16;
    const bool active = (m0 < M);
    const int quad = lane >> 4;
    const int l15 = lane & 15;

    if (active) {
        f32x4 acc[8];
#pragma unroll
        for (int i = 0; i < 8; ++i) acc[i] = (f32x4){0.f, 0.f, 0.f, 0.f};
        for (int kt = 0; kt < 4; ++kt) {
            bf16x8 a = cvt8(X + (size_t)(m0 + l15) * 128 + kt * 32 + quad * 8);
#pragma unroll
            for (int nt = 0; nt < 8; ++nt) {
                bf16x8 b = *reinterpret_cast<const bf16x8*>(W1p + (size_t)(((kt * 8 + nt) * 64 + lane) * 8));
                acc[nt] = __builtin_amdgcn_mfma_f32_16x16x32_bf16(a, b, acc[nt], 0, 0, 0);
            }
        }
#pragma unroll
        for (int nt = 0; nt < 8; ++nt) {
            int col = nt * 16 + l15;
            float bv = (col < 64) ? b1a[col] : b1b[col - 64];
#pragma unroll
            for (int r = 0; r < 4; ++r) {
                float v = fmaxf(acc[nt][r] + bv, 0.f);
                lds[wv][quad * 4 + r][col] = f2bf(v);
            }
        }
    }
    __syncthreads();
    if (!active) return;

    float w0 = cW2[lane * 2 + 0];
    float w1 = cW2[lane * 2 + 1];
    float w2 = rW2[lane];
    float cb0 = cb2[0], cb1v = cb2[1], rb = rb2[0];
    for (int r = 0; r < 16; ++r) {
        float t1 = bf2f(lds[wv][r][lane]);
        float t2 = bf2f(lds[wv][r][64 + lane]);
        float s0 = t1 * w0;
        float s1 = t1 * w1;
        float s2 = t2 * w2;
        for (int off = 32; off > 0; off >>= 1) {
            s0 += __shfl_xor(s0, off);
            s1 += __shfl_xor(s1, off);
            s2 += __shfl_xor(s2, off);
        }
        if (lane == 0) {
            int row = m0 + r;
            pred[(size_t)row * 2 + 0] = s0 + cb0;
            pred[(size_t)row * 2 + 1] = s1 + cb1v;
            float z = s2 + rb;
            risk[row] = 1.f / (1.f + __expf(-z));
        }
    }
}

// ---------------- host ----------------
#define OFF_CNT_M  ((size_t)0)
#define OFF_CNT_C  ((size_t)262144)
#define OFF_BKT_M  ((size_t)1  << 20)
#define OFF_BKT_C  ((size_t)14 << 20)
#define OFF_HM     ((size_t)27 << 20)
#define OFF_PACK   ((size_t)40 << 20)

extern "C" void kernel_launch(void* const* d_in, const int* in_sizes, int n_in,
                              void* d_out, int out_size, void* d_ws, size_t ws_size,
                              hipStream_t stream)
{
    const float* x_card   = (const float*)d_in[0];
    const float* x_merch  = (const float*)d_in[1];
    const int* src_cm     = (const int*)d_in[2];
    const int* dst_cm     = (const int*)d_in[3];
    const int* src_mc     = (const int*)d_in[4];
    const int* dst_mc     = (const int*)d_in[5];
    const float* Wl0_cm   = (const float*)d_in[6];
    const float* bl0_cm   = (const float*)d_in[7];
    const float* Wr0_cm   = (const float*)d_in[8];
    const float* Wl0_mc   = (const float*)d_in[9];
    const float* bl0_mc   = (const float*)d_in[10];
    const float* Wr0_mc   = (const float*)d_in[11];
    const float* Wl1_cm   = (const float*)d_in[12];
    const float* bl1_cm   = (const float*)d_in[13];
    const float* Wr1_cm   = (const float*)d_in[14];
    const float* Wl1_mc   = (const float*)d_in[15];
    const float* bl1_mc   = (const float*)d_in[16];
    const float* Wr1_mc   = (const float*)d_in[17];
    const float* cW1_card = (const float*)d_in[18];
    const float* cb1_card = (const float*)d_in[19];
    const float* cW2_card = (const float*)d_in[20];
    const float* cb2_card = (const float*)d_in[21];
    const float* cW1_mer  = (const float*)d_in[22];
    const float* cb1_mer  = (const float*)d_in[23];
    const float* cW2_mer  = (const float*)d_in[24];
    const float* cb2_mer  = (const float*)d_in[25];
    const float* rW1      = (const float*)d_in[26];
    const float* rb1      = (const float*)d_in[27];
    const float* rW2      = (const float*)d_in[28];
    const float* rb2      = (const float*)d_in[29];

    const int nCard  = in_sizes[0] / 64;   // 100000
    const int nMerch = in_sizes[1] / 64;   // 50000
    const int E      = in_sizes[2];        // 1000000

    char* ws = (char*)d_ws;
    int* cnt_m    = (int*)(ws + OFF_CNT_M);
    int* cnt_c    = (int*)(ws + OFF_CNT_C);
    u32* bucket_m = (u32*)(ws + OFF_BKT_M);
    u16* bucket_c = (u16*)(ws + OFF_BKT_C);
    u16* h_m      = (u16*)(ws + OFF_HM);        // layer-0 merchant hidden, bf16
    u16* pw       = (u16*)(ws + OFF_PACK);      // 10 slots * 16384 u16
    u16* pWl0_cm = pw + 0 * 16384;
    u16* pWr0_cm = pw + 1 * 16384;
    u16* pWl0_mc = pw + 2 * 16384;
    u16* pWr0_mc = pw + 3 * 16384;
    u16* pWl1_cm = pw + 4 * 16384;
    u16* pWr1_cm = pw + 5 * 16384;
    u16* pWl1_mc = pw + 6 * 16384;
    u16* pWr1_mc = pw + 7 * 16384;
    u16* pHeadC  = pw + 8 * 16384;   // [cW1_card | rW1]
    u16* pHeadM  = pw + 9 * 16384;   // [cW1_merch | rW1]

    float* out     = (float*)d_out;
    float* o_hc2   = out;
    float* o_hm2   = o_hc2 + (size_t)nCard * 128;
    float* o_predc = o_hm2 + (size_t)nMerch * 128;
    float* o_predm = o_predc + (size_t)nCard * 2;
    float* o_riskc = o_predm + (size_t)nMerch * 2;
    float* o_riskm = o_riskc + (size_t)nCard;

    // zero the two count arrays (ws is poisoned 0xAA before every call)
    hipMemsetAsync(ws, 0, OFF_CNT_C + (size_t)nCard * sizeof(int), stream);

    PackArgs pa;
    pa.d[0]  = { Wl0_cm,   pWl0_cm,  64, 128, 0 };
    pa.d[1]  = { Wr0_cm,   pWr0_cm,  64, 128, 0 };
    pa.d[2]  = { Wl0_mc,   pWl0_mc,  64, 128, 0 };
    pa.d[3]  = { Wr0_mc,   pWr0_mc,  64, 128, 0 };
    pa.d[4]  = { Wl1_cm,   pWl1_cm, 128, 128, 0 };
    pa.d[5]  = { Wr1_cm,   pWr1_cm, 128, 128, 0 };
    pa.d[6]  = { Wl1_mc,   pWl1_mc, 128, 128, 0 };
    pa.d[7]  = { Wr1_mc,   pWr1_mc, 128, 128, 0 };
    pa.d[8]  = { cW1_card, pHeadC,  128,  64, 0 };
    pa.d[9]  = { rW1,      pHeadC,  128,  64, 4 };
    pa.d[10] = { cW1_mer,  pHeadM,  128,  64, 0 };
    pa.d[11] = { rW1,      pHeadM,  128,  64, 4 };
    pack_all<<<dim3(64, 12), 256, 0, stream>>>(pa);

    build_buckets<<<(2 * E + 255) / 256, 256, 0, stream>>>(
        src_cm, dst_cm, src_mc, dst_mc, cnt_m, bucket_m, cnt_c, bucket_c, E);

    // ---- layer 0 ----
    // merchant: gather fp32 x_card, lin_r fp32 x_merch -> h_m (bf16, ws)
    sage_fused<u32, true, true, false><<<(nMerch + 63) / 64, 256, 0, stream>>>(
        x_card, bucket_m, cnt_m, pWl0_cm, x_merch, pWr0_cm, bl0_cm, h_m, nMerch, 64);
    // card: gather fp32 x_merch, lin_r fp32 x_card -> h_c (fp32, in o_hc2)
    sage_fused<u16, true, true, true><<<(nCard + 63) / 64, 256, 0, stream>>>(
        x_merch, bucket_c, cnt_c, pWl0_mc, x_card, pWr0_mc, bl0_mc, o_hc2, nCard, 64);

    // ---- layer 1 ----
    // merchant first: gathers h_c (fp32, o_hc2) before card update overwrites it
    sage_fused<u32, true, false, true><<<(nMerch + 63) / 64, 256, 0, stream>>>(
        o_hc2, bucket_m, cnt_m, pWl1_cm, h_m, pWr1_cm, bl1_cm, o_hm2, nMerch, 128);
    // card: gathers h_m (bf16, ws), lin_r on own rows of o_hc2 (fp32), in-place row-disjoint
    sage_fused<u16, false, true, true><<<(nCard + 63) / 64, 256, 0, stream>>>(
        h_m, bucket_c, cnt_c, pWl1_mc, o_hc2, pWr1_mc, bl1_mc, o_hc2, nCard, 128);

    // ---- heads ----
    head_fused<<<(nCard + 63) / 64, 256, 0, stream>>>(
        o_hc2, pHeadC, cb1_card, rb1, cW2_card, cb2_card, rW2, rb2, o_predc, o_riskc, nCard);
    head_fused<<<(nMerch + 63) / 64, 256, 0, stream>>>(
        o_hm2, pHeadM, cb1_mer, rb1, cW2_mer, cb2_mer, rW2, rb2, o_predm, o_riskm, nMerch);
}

// Round 4
// 660.141 us; speedup vs baseline: 1.4815x; 1.4815x over previous
//
#include <hip/hip_runtime.h>

// HeteroGraphSAGE on MI355X — fp32 I/O, bf16 MFMA internals, MLP-widened gather.
//
// R3 change: gather-mean restructured from serial-per-neighbor (1 load in
// flight) to 4 neighbor-groups x 16 feature-lanes x 2 accumulator banks
// (8 neighbors / step, 4 independent loads in flight), cross-group reduce
// via shfl_xor(16/32). K is now a template constant.
//
// ws layout (bytes), total ~40.4 MiB:
//   cnt_m    @ 0        (50000*4)
//   cnt_c    @ 256K     (100000*4)
//   bucket_m @ 1  MiB   (50000*64*4  u32 card ids)
//   bucket_c @ 14 MiB   (100000*64*2 u16 merchant ids)
//   h_m      @ 27 MiB   (50000*128*2 bf16)
//   packed   @ 40 MiB   (10 * 32 KiB bf16)
// h_c (layer-0 card hidden) lives fp32 in d_out's h_c2 slot; layer-1 merchant
// gathers it, then layer-1 card updates it in place (row-disjoint).

typedef unsigned short u16;
typedef unsigned int u32;
typedef short bf16x8 __attribute__((ext_vector_type(8)));
typedef float f32x4 __attribute__((ext_vector_type(4)));
typedef u16 u16x4 __attribute__((ext_vector_type(4)));
typedef u16 u16x8 __attribute__((ext_vector_type(8)));

#define CAP 64
#define LDS_PAD 8   // row stride 136 u16 = 272 B (16B-aligned)

__device__ __forceinline__ float bf2f(u16 u) {
    union { u32 i; float f; } v; v.i = ((u32)u) << 16; return v.f;
}
__device__ __forceinline__ u16 f2bf(float f) {
    union { float f; u32 i; } v; v.f = f;
    u32 i = v.i;
    return (u16)((i + 0x7FFFu + ((i >> 16) & 1u)) >> 16);   // RNE
}
__device__ __forceinline__ bf16x8 cvt8(const float* p) {
    bf16x8 r;
#pragma unroll
    for (int i = 0; i < 8; ++i) r[i] = (short)f2bf(p[i]);
    return r;
}

// ---------------- weight packing: fp32 W[K,Nsrc] -> bf16 MFMA B fragments ----------------
struct PackDesc { const float* src; u16* dst; int K; int Nsrc; int ntOff; };
struct PackArgs { PackDesc d[12]; };

__global__ void __launch_bounds__(256) pack_all(PackArgs pa) {
    PackDesc pd = pa.d[blockIdx.y];
    int idx = blockIdx.x * 256 + threadIdx.x;          // < 16384
    int j = idx & 7;
    int lane = (idx >> 3) & 63;
    int t = idx >> 9;
    int nLocal = pd.Nsrc >> 4;
    int ntl = t % nLocal;
    int kt = t / nLocal;
    if (kt >= (pd.K >> 5)) return;
    int k = kt * 32 + ((lane >> 4) << 3) + j;
    int n = ntl * 16 + (lane & 15);
    pd.dst[(((kt * 8 + pd.ntOff + ntl) * 64) + lane) * 8 + j] = f2bf(pd.src[k * pd.Nsrc + n]);
}

// ---------------- bucket build ----------------
__global__ void __launch_bounds__(256) build_buckets(
    const int* __restrict__ src_cm, const int* __restrict__ dst_cm,
    const int* __restrict__ src_mc, const int* __restrict__ dst_mc,
    int* __restrict__ cnt_m, u32* __restrict__ bucket_m,
    int* __restrict__ cnt_c, u16* __restrict__ bucket_c, int E)
{
    int i = blockIdx.x * 256 + threadIdx.x;
    if (i < E) {
        int d = dst_cm[i];
        int slot = atomicAdd(&cnt_m[d], 1);
        if (slot < CAP) bucket_m[(size_t)d * CAP + slot] = (u32)src_cm[i];
    } else if (i < 2 * E) {
        int j = i - E;
        int d = dst_mc[j];
        int slot = atomicAdd(&cnt_c[d], 1);
        if (slot < CAP) bucket_c[(size_t)d * CAP + slot] = (u16)src_mc[j];
    }
}

// ---------------- fused SAGE layer ----------------
// out[M,128] = relu(mean_nbr(Xsrc) @ Wl + Xdst @ Wr + bias)
// Gather: 4 neighbor-groups (nb=lane>>4) x 16 feature-lanes (fl=lane&15),
// 2 accumulator banks -> 8 neighbors per step, 2-4 loads in flight.
template<typename IdxT, int KF, bool SRCF, bool DSTF, bool OUTF>
__global__ void __launch_bounds__(256) sage_fused(
    const void* __restrict__ Xsrc_, const IdxT* __restrict__ adj,
    const int* __restrict__ cnt,
    const u16* __restrict__ Wlp, const void* __restrict__ Xdst_,
    const u16* __restrict__ Wrp, const float* __restrict__ bias,
    void* __restrict__ out_, int M)
{
    constexpr int NV = KF / 16;         // floats per lane per neighbor chunk
    __shared__ alignas(16) u16 lds[4][16][128 + LDS_PAD];
    const int lane = threadIdx.x & 63;
    const int wv = threadIdx.x >> 6;
    const int m0 = (blockIdx.x * 4 + wv) * 16;
    const bool active = (m0 < M);
    const int quad = lane >> 4;
    const int l15 = lane & 15;
    const int nb = quad;                // neighbor group 0..3
    const int fl = l15;                 // feature lane 0..15

    if (active) {
        const float* srcF = (const float*)Xsrc_;
        const u16*   srcH = (const u16*)Xsrc_;
        for (int r = 0; r < 16; ++r) {
            int node = m0 + r;
            int c = cnt[node];
            int cc = min(c, CAP);
            int sidx = (lane < cc) ? (int)adj[(size_t)node * CAP + lane] : 0;
            float inv = 1.f / (float)max(c, 1);
            float acc0[NV], acc1[NV];
#pragma unroll
            for (int i = 0; i < NV; ++i) { acc0[i] = 0.f; acc1[i] = 0.f; }
            for (int t = 0; t < cc; t += 8) {
                int k0 = t + nb;
                int k1 = t + nb + 4;
                int s0 = __shfl(sidx, k0);
                int s1 = __shfl(sidx, k1);
                bool p0 = k0 < cc;
                bool p1 = k1 < cc;
                if constexpr (SRCF) {
                    const f32x4* q0 = (const f32x4*)(srcF + (size_t)s0 * KF + fl * NV);
                    const f32x4* q1 = (const f32x4*)(srcF + (size_t)s1 * KF + fl * NV);
                    f32x4 u0 = q0[0];
                    f32x4 u1 = q1[0];
                    if constexpr (NV == 8) {
                        f32x4 w0 = q0[1];
                        f32x4 w1 = q1[1];
#pragma unroll
                        for (int i = 0; i < 4; ++i) {
                            acc0[4 + i] += p0 ? w0[i] : 0.f;
                            acc1[4 + i] += p1 ? w1[i] : 0.f;
                        }
                    }
#pragma unroll
                    for (int i = 0; i < 4; ++i) {
                        acc0[i] += p0 ? u0[i] : 0.f;
                        acc1[i] += p1 ? u1[i] : 0.f;
                    }
                } else {
                    // bf16 source, KF==128: 8 u16 = 16 B per lane per neighbor
                    bf16x8 u0 = *(const bf16x8*)(srcH + (size_t)s0 * KF + fl * 8);
                    bf16x8 u1 = *(const bf16x8*)(srcH + (size_t)s1 * KF + fl * 8);
#pragma unroll
                    for (int i = 0; i < 8; ++i) {
                        acc0[i] += p0 ? bf2f((u16)u0[i]) : 0.f;
                        acc1[i] += p1 ? bf2f((u16)u1[i]) : 0.f;
                    }
                }
            }
            // merge banks + cross-group reduce (4 groups: xor 16, 32)
            u16 packed[NV];
#pragma unroll
            for (int i = 0; i < NV; ++i) {
                float m = acc0[i] + acc1[i];
                m += __shfl_xor(m, 16);
                m += __shfl_xor(m, 32);
                packed[i] = f2bf(m * inv);
            }
            if (nb == 0) {
                if constexpr (NV == 8) {
                    *(u16x8*)&lds[wv][r][fl * 8] = *(const u16x8*)packed;
                } else {
                    *(u16x4*)&lds[wv][r][fl * 4] = *(const u16x4*)packed;
                }
            }
        }
    }
    __syncthreads();
    if (!active) return;

    constexpr int KT = KF >> 5;
    f32x4 acc[8];
#pragma unroll
    for (int i = 0; i < 8; ++i) acc[i] = (f32x4){0.f, 0.f, 0.f, 0.f};

#pragma unroll
    for (int kt = 0; kt < KT; ++kt) {
        bf16x8 a = *reinterpret_cast<const bf16x8*>(&lds[wv][l15][kt * 32 + quad * 8]);
#pragma unroll
        for (int nt = 0; nt < 8; ++nt) {
            bf16x8 b = *reinterpret_cast<const bf16x8*>(Wlp + (size_t)(((kt * 8 + nt) * 64 + lane) * 8));
            acc[nt] = __builtin_amdgcn_mfma_f32_16x16x32_bf16(a, b, acc[nt], 0, 0, 0);
        }
    }
#pragma unroll
    for (int kt = 0; kt < KT; ++kt) {
        bf16x8 a;
        if constexpr (DSTF) a = cvt8((const float*)Xdst_ + (size_t)(m0 + l15) * KF + kt * 32 + quad * 8);
        else                a = *reinterpret_cast<const bf16x8*>((const u16*)Xdst_ + (size_t)(m0 + l15) * KF + kt * 32 + quad * 8);
#pragma unroll
        for (int nt = 0; nt < 8; ++nt) {
            bf16x8 b = *reinterpret_cast<const bf16x8*>(Wrp + (size_t)(((kt * 8 + nt) * 64 + lane) * 8));
            acc[nt] = __builtin_amdgcn_mfma_f32_16x16x32_bf16(a, b, acc[nt], 0, 0, 0);
        }
    }
    // epilogue: C/D layout col = lane&15 (within 16-col tile), row = quad*4 + r
#pragma unroll
    for (int nt = 0; nt < 8; ++nt) {
        int col = nt * 16 + l15;
        float bv = bias[col];
#pragma unroll
        for (int r = 0; r < 4; ++r) {
            int row = m0 + quad * 4 + r;
            float v = fmaxf(acc[nt][r] + bv, 0.f);
            if constexpr (OUTF) ((float*)out_)[(size_t)row * 128 + col] = v;
            else                ((u16*)out_)[(size_t)row * 128 + col] = f2bf(v);
        }
    }
}

// ---------------- fused classifier + risk heads (X fp32) ----------------
__global__ void __launch_bounds__(256) head_fused(
    const float* __restrict__ X, const u16* __restrict__ W1p,
    const float* __restrict__ b1a, const float* __restrict__ b1b,
    const float* __restrict__ cW2, const float* __restrict__ cb2,
    const float* __restrict__ rW2, const float* __restrict__ rb2,
    float* __restrict__ pred, float* __restrict__ risk, int M)
{
    __shared__ alignas(16) u16 lds[4][16][128 + LDS_PAD];
    const int lane = threadIdx.x & 63;
    const int wv = threadIdx.x >> 6;
    const int m0 = (blockIdx.x * 4 + wv) * 16;
    const bool active = (m0 < M);
    const int quad = lane >> 4;
    const int l15 = lane & 15;

    if (active) {
        f32x4 acc[8];
#pragma unroll
        for (int i = 0; i < 8; ++i) acc[i] = (f32x4){0.f, 0.f, 0.f, 0.f};
#pragma unroll
        for (int kt = 0; kt < 4; ++kt) {
            bf16x8 a = cvt8(X + (size_t)(m0 + l15) * 128 + kt * 32 + quad * 8);
#pragma unroll
            for (int nt = 0; nt < 8; ++nt) {
                bf16x8 b = *reinterpret_cast<const bf16x8*>(W1p + (size_t)(((kt * 8 + nt) * 64 + lane) * 8));
                acc[nt] = __builtin_amdgcn_mfma_f32_16x16x32_bf16(a, b, acc[nt], 0, 0, 0);
            }
        }
#pragma unroll
        for (int nt = 0; nt < 8; ++nt) {
            int col = nt * 16 + l15;
            float bv = (col < 64) ? b1a[col] : b1b[col - 64];
#pragma unroll
            for (int r = 0; r < 4; ++r) {
                float v = fmaxf(acc[nt][r] + bv, 0.f);
                lds[wv][quad * 4 + r][col] = f2bf(v);
            }
        }
    }
    __syncthreads();
    if (!active) return;

    float w0 = cW2[lane * 2 + 0];
    float w1 = cW2[lane * 2 + 1];
    float w2 = rW2[lane];
    float cb0 = cb2[0], cb1v = cb2[1], rb = rb2[0];
    for (int r = 0; r < 16; ++r) {
        float t1 = bf2f(lds[wv][r][lane]);
        float t2 = bf2f(lds[wv][r][64 + lane]);
        float s0 = t1 * w0;
        float s1 = t1 * w1;
        float s2 = t2 * w2;
        for (int off = 32; off > 0; off >>= 1) {
            s0 += __shfl_xor(s0, off);
            s1 += __shfl_xor(s1, off);
            s2 += __shfl_xor(s2, off);
        }
        if (lane == 0) {
            int row = m0 + r;
            pred[(size_t)row * 2 + 0] = s0 + cb0;
            pred[(size_t)row * 2 + 1] = s1 + cb1v;
            float z = s2 + rb;
            risk[row] = 1.f / (1.f + __expf(-z));
        }
    }
}

// ---------------- host ----------------
#define OFF_CNT_M  ((size_t)0)
#define OFF_CNT_C  ((size_t)262144)
#define OFF_BKT_M  ((size_t)1  << 20)
#define OFF_BKT_C  ((size_t)14 << 20)
#define OFF_HM     ((size_t)27 << 20)
#define OFF_PACK   ((size_t)40 << 20)

extern "C" void kernel_launch(void* const* d_in, const int* in_sizes, int n_in,
                              void* d_out, int out_size, void* d_ws, size_t ws_size,
                              hipStream_t stream)
{
    const float* x_card   = (const float*)d_in[0];
    const float* x_merch  = (const float*)d_in[1];
    const int* src_cm     = (const int*)d_in[2];
    const int* dst_cm     = (const int*)d_in[3];
    const int* src_mc     = (const int*)d_in[4];
    const int* dst_mc     = (const int*)d_in[5];
    const float* Wl0_cm   = (const float*)d_in[6];
    const float* bl0_cm   = (const float*)d_in[7];
    const float* Wr0_cm   = (const float*)d_in[8];
    const float* Wl0_mc   = (const float*)d_in[9];
    const float* bl0_mc   = (const float*)d_in[10];
    const float* Wr0_mc   = (const float*)d_in[11];
    const float* Wl1_cm   = (const float*)d_in[12];
    const float* bl1_cm   = (const float*)d_in[13];
    const float* Wr1_cm   = (const float*)d_in[14];
    const float* Wl1_mc   = (const float*)d_in[15];
    const float* bl1_mc   = (const float*)d_in[16];
    const float* Wr1_mc   = (const float*)d_in[17];
    const float* cW1_card = (const float*)d_in[18];
    const float* cb1_card = (const float*)d_in[19];
    const float* cW2_card = (const float*)d_in[20];
    const float* cb2_card = (const float*)d_in[21];
    const float* cW1_mer  = (const float*)d_in[22];
    const float* cb1_mer  = (const float*)d_in[23];
    const float* cW2_mer  = (const float*)d_in[24];
    const float* cb2_mer  = (const float*)d_in[25];
    const float* rW1      = (const float*)d_in[26];
    const float* rb1      = (const float*)d_in[27];
    const float* rW2      = (const float*)d_in[28];
    const float* rb2      = (const float*)d_in[29];

    const int nCard  = in_sizes[0] / 64;   // 100000
    const int nMerch = in_sizes[1] / 64;   // 50000
    const int E      = in_sizes[2];        // 1000000

    char* ws = (char*)d_ws;
    int* cnt_m    = (int*)(ws + OFF_CNT_M);
    int* cnt_c    = (int*)(ws + OFF_CNT_C);
    u32* bucket_m = (u32*)(ws + OFF_BKT_M);
    u16* bucket_c = (u16*)(ws + OFF_BKT_C);
    u16* h_m      = (u16*)(ws + OFF_HM);        // layer-0 merchant hidden, bf16
    u16* pw       = (u16*)(ws + OFF_PACK);      // 10 slots * 16384 u16
    u16* pWl0_cm = pw + 0 * 16384;
    u16* pWr0_cm = pw + 1 * 16384;
    u16* pWl0_mc = pw + 2 * 16384;
    u16* pWr0_mc = pw + 3 * 16384;
    u16* pWl1_cm = pw + 4 * 16384;
    u16* pWr1_cm = pw + 5 * 16384;
    u16* pWl1_mc = pw + 6 * 16384;
    u16* pWr1_mc = pw + 7 * 16384;
    u16* pHeadC  = pw + 8 * 16384;   // [cW1_card | rW1]
    u16* pHeadM  = pw + 9 * 16384;   // [cW1_merch | rW1]

    float* out     = (float*)d_out;
    float* o_hc2   = out;
    float* o_hm2   = o_hc2 + (size_t)nCard * 128;
    float* o_predc = o_hm2 + (size_t)nMerch * 128;
    float* o_predm = o_predc + (size_t)nCard * 2;
    float* o_riskc = o_predm + (size_t)nMerch * 2;
    float* o_riskm = o_riskc + (size_t)nCard;

    // zero the two count arrays (ws is poisoned 0xAA before every call)
    hipMemsetAsync(ws, 0, OFF_CNT_C + (size_t)nCard * sizeof(int), stream);

    PackArgs pa;
    pa.d[0]  = { Wl0_cm,   pWl0_cm,  64, 128, 0 };
    pa.d[1]  = { Wr0_cm,   pWr0_cm,  64, 128, 0 };
    pa.d[2]  = { Wl0_mc,   pWl0_mc,  64, 128, 0 };
    pa.d[3]  = { Wr0_mc,   pWr0_mc,  64, 128, 0 };
    pa.d[4]  = { Wl1_cm,   pWl1_cm, 128, 128, 0 };
    pa.d[5]  = { Wr1_cm,   pWr1_cm, 128, 128, 0 };
    pa.d[6]  = { Wl1_mc,   pWl1_mc, 128, 128, 0 };
    pa.d[7]  = { Wr1_mc,   pWr1_mc, 128, 128, 0 };
    pa.d[8]  = { cW1_card, pHeadC,  128,  64, 0 };
    pa.d[9]  = { rW1,      pHeadC,  128,  64, 4 };
    pa.d[10] = { cW1_mer,  pHeadM,  128,  64, 0 };
    pa.d[11] = { rW1,      pHeadM,  128,  64, 4 };
    pack_all<<<dim3(64, 12), 256, 0, stream>>>(pa);

    build_buckets<<<(2 * E + 255) / 256, 256, 0, stream>>>(
        src_cm, dst_cm, src_mc, dst_mc, cnt_m, bucket_m, cnt_c, bucket_c, E);

    // ---- layer 0 ----
    sage_fused<u32, 64, true, true, false><<<(nMerch + 63) / 64, 256, 0, stream>>>(
        x_card, bucket_m, cnt_m, pWl0_cm, x_merch, pWr0_cm, bl0_cm, h_m, nMerch);
    sage_fused<u16, 64, true, true, true><<<(nCard + 63) / 64, 256, 0, stream>>>(
        x_merch, bucket_c, cnt_c, pWl0_mc, x_card, pWr0_mc, bl0_mc, o_hc2, nCard);

    // ---- layer 1 ----
    // merchant first: gathers h_c (fp32, o_hc2) before card update overwrites it
    sage_fused<u32, 128, true, false, true><<<(nMerch + 63) / 64, 256, 0, stream>>>(
        o_hc2, bucket_m, cnt_m, pWl1_cm, h_m, pWr1_cm, bl1_cm, o_hm2, nMerch);
    // card: gathers h_m (bf16, ws), lin_r on own rows of o_hc2 (fp32), in-place row-disjoint
    sage_fused<u16, 128, false, true, true><<<(nCard + 63) / 64, 256, 0, stream>>>(
        h_m, bucket_c, cnt_c, pWl1_mc, o_hc2, pWr1_mc, bl1_mc, o_hc2, nCard);

    // ---- heads ----
    head_fused<<<(nCard + 63) / 64, 256, 0, stream>>>(
        o_hc2, pHeadC, cb1_card, rb1, cW2_card, cb2_card, rW2, rb2, o_predc, o_riskc, nCard);
    head_fused<<<(nMerch + 63) / 64, 256, 0, stream>>>(
        o_hm2, pHeadM, cb1_mer, rb1, cW2_mer, cb2_mer, rW2, rb2, o_predm, o_riskm, nMerch);
}